// Round 1
// baseline (47.141 us; speedup 1.0000x reference)
//
#include <hip/hip_runtime.h>
#include <math.h>

#define NPTS   30000
#define NB     16
#define CNT_W  65
#define CNT_SZ (65 * 65)      // 4225
#define NIMG   64             // 2 rot * 2 clouds * 16 batches
#define IMG_SZ 4096           // 64*64

// ---------------- init: zero count grids + output ----------------
__global__ void init_kernel(unsigned* cnts, float* out, int ncnt) {
    int i = blockIdx.x * blockDim.x + threadIdx.x;
    if (i < ncnt) cnts[i] = 0u;
    if (i == 0) out[0] = 0.0f;
}

__device__ inline void eul2rot(const float* t, float R[9]) {
    float s0 = sinf(t[0]), s1 = sinf(t[1]), s2 = sinf(t[2]);
    float c0 = cosf(t[0]), c1 = cosf(t[1]), c2 = cosf(t[2]);
    R[0] = c1 * c2; R[1] = s0 * s1 * c2 - s2 * c0; R[2] = s1 * c0 * c2 + s0 * s2;
    R[3] = s2 * c1; R[4] = s0 * s1 * s2 + c0 * c2; R[5] = s1 * s2 * c0 - s0 * c2;
    R[6] = -s1;     R[7] = s0 * c1;                R[8] = c0 * c1;
}

// ---------------- histogram of rounded projected points ----------------
// grid: 64 images * 4 splits = 256 blocks, 256 threads
__global__ __launch_bounds__(256) void hist_kernel(const float* __restrict__ pc1,
                                                   const float* __restrict__ pc2,
                                                   const float* __restrict__ rot,
                                                   unsigned* __restrict__ cnts) {
    __shared__ unsigned lcnt[CNT_SZ];
    int bid   = blockIdx.x;
    int split = bid & 3;
    int imgi  = bid >> 2;
    int b = imgi & 15;
    int c = (imgi >> 4) & 1;
    int r = imgi >> 5;

    for (int i = threadIdx.x; i < CNT_SZ; i += 256) lcnt[i] = 0u;

    float R[9];
    eul2rot(rot + 3 * r, R);
    const float* pc = (c ? pc2 : pc1) + (size_t)b * NPTS * 3;
    __syncthreads();

    const int chunk = NPTS / 4;
    int start = split * chunk, end = start + chunk;
    for (int p = start + (int)threadIdx.x; p < end; p += 256) {
        float x  = pc[3 * p + 0];
        float y  = pc[3 * p + 1];
        float zz = pc[3 * p + 2];
        float cx = R[0] * x + R[1] * y + R[2] * zz;
        float cy = R[3] * x + R[4] * y + R[5] * zz;
        float cz = R[6] * x + R[7] * y + R[8] * zz;
        float z  = cz + 2.5f;
        float u  = 120.0f * cx / z + 36.0f;
        float v  = 120.0f * cy / z + 36.0f;
        int x4 = (int)rintf(u);   // round-half-even, matches jnp.round
        int y4 = (int)rintf(v);
        if (x4 >= 0 && x4 <= 64 && y4 >= 0 && y4 <= 64)
            atomicAdd(&lcnt[x4 * CNT_W + y4], 1u);
    }
    __syncthreads();

    unsigned* g = cnts + (size_t)imgi * CNT_SZ;
    for (int i = threadIdx.x; i < CNT_SZ; i += 256) {
        unsigned v = lcnt[i];
        if (v) atomicAdd(&g[i], v);
    }
}

// ---------------- 5x5 conv + per-image max ----------------
// grid: 64 blocks (one per image), 256 threads
__global__ __launch_bounds__(256) void conv_kernel(const unsigned* __restrict__ cnts,
                                                   float* __restrict__ imgs,
                                                   float* __restrict__ maxes) {
    __shared__ float lc[CNT_SZ];
    __shared__ float wmax[4];
    int imgi = blockIdx.x;
    const unsigned* g = cnts + (size_t)imgi * CNT_SZ;
    for (int i = threadIdx.x; i < CNT_SZ; i += 256) lc[i] = (float)g[i];

    // GK[i][j] = exp(-sqrt((i-5)^2+(j-5)^2)/0.4), i,j in 0..4
    float GK[25];
#pragma unroll
    for (int i = 0; i < 5; i++)
#pragma unroll
        for (int j = 0; j < 5; j++) {
            float d = sqrtf((float)((i - 5) * (i - 5) + (j - 5) * (j - 5)));
            GK[i * 5 + j] = expf(-d / 0.4f);
        }
    __syncthreads();

    float* img = imgs + (size_t)imgi * IMG_SZ;
    float lmax = 0.0f;
    for (int o = threadIdx.x; o < IMG_SZ; o += 256) {
        int px = o >> 6, py = o & 63;
        float s = 0.0f;
#pragma unroll
        for (int i = 0; i < 5; i++) {
            int x = px + 2 + i;
#pragma unroll
            for (int j = 0; j < 5; j++) {
                int y = py + 2 + j;
                if (x <= 64 && y <= 64) s += GK[i * 5 + j] * lc[x * CNT_W + y];
            }
        }
        img[o] = s;
        lmax = fmaxf(lmax, s);
    }
    // reduce max over block (4 waves of 64)
#pragma unroll
    for (int off = 32; off > 0; off >>= 1) lmax = fmaxf(lmax, __shfl_down(lmax, off));
    int wave = threadIdx.x >> 6;
    if ((threadIdx.x & 63) == 0) wmax[wave] = lmax;
    __syncthreads();
    if (threadIdx.x == 0) {
        float m = fmaxf(fmaxf(wmax[0], wmax[1]), fmaxf(wmax[2], wmax[3]));
        maxes[imgi] = m;
    }
}

// ---------------- BCE sum ----------------
// grid: 32 blocks (2 rot * 16 batches), 256 threads
__global__ __launch_bounds__(256) void bce_kernel(const float* __restrict__ imgs,
                                                  const float* __restrict__ maxes,
                                                  float* __restrict__ out) {
    __shared__ float wsum[4];
    int bid = blockIdx.x;        // r*16 + b
    int b = bid & 15, r = bid >> 4;
    int i1 = (r * 2 + 0) * NB + b;
    int i2 = (r * 2 + 1) * NB + b;
    const float* im1 = imgs + (size_t)i1 * IMG_SZ;
    const float* im2 = imgs + (size_t)i2 * IMG_SZ;
    float m1 = maxes[i1], m2 = maxes[i2];

    float s = 0.0f;
    for (int o = threadIdx.x; o < IMG_SZ; o += 256) {
        float e1 = im1[o] / m1;
        float e2 = im2[o] / m2;
        float lp = fmaxf(logf(e1), -100.0f);
        float lq = fmaxf(logf(1.0f - e1), -100.0f);
        s += e2 * lp + (1.0f - e2) * lq;
    }
#pragma unroll
    for (int off = 32; off > 0; off >>= 1) s += __shfl_down(s, off);
    int wave = threadIdx.x >> 6;
    if ((threadIdx.x & 63) == 0) wsum[wave] = s;
    __syncthreads();
    if (threadIdx.x == 0) {
        float tot = wsum[0] + wsum[1] + wsum[2] + wsum[3];
        atomicAdd(out, -tot);
    }
}

extern "C" void kernel_launch(void* const* d_in, const int* in_sizes, int n_in,
                              void* d_out, int out_size, void* d_ws, size_t ws_size,
                              hipStream_t stream) {
    const float* pc1 = (const float*)d_in[0];
    const float* pc2 = (const float*)d_in[1];
    const float* rot = (const float*)d_in[2];
    float* out = (float*)d_out;

    // workspace layout
    unsigned* cnts = (unsigned*)d_ws;                      // 64 * 4225 u32
    float* imgs  = (float*)d_ws + NIMG * CNT_SZ;           // 64 * 4096 f32
    float* maxes = imgs + NIMG * IMG_SZ;                   // 64 f32

    int ncnt = NIMG * CNT_SZ;
    init_kernel<<<(ncnt + 255) / 256, 256, 0, stream>>>(cnts, out, ncnt);
    hist_kernel<<<NIMG * 4, 256, 0, stream>>>(pc1, pc2, rot, cnts);
    conv_kernel<<<NIMG, 256, 0, stream>>>(cnts, imgs, maxes);
    bce_kernel<<<32, 256, 0, stream>>>(imgs, maxes, out);
}

// Round 2
// 22.397 us; speedup vs baseline: 2.1048x; 2.1048x over previous
//
#include <hip/hip_runtime.h>
#include <math.h>

#define NPTS    30000
#define NB      16
#define CNT_W   65
#define CNT_SZ  (65 * 65)     // 4225
#define NIMG    64            // 2 rot * 2 clouds * 16 batches
#define IMG_SZ  4096          // 64*64
#define NSPLIT  4
#define GPS     (NPTS / 4 / NSPLIT)   // 1875 four-point groups per split

__device__ inline void eul2rot(const float* t, float R[9]) {
    float s0 = sinf(t[0]), s1 = sinf(t[1]), s2 = sinf(t[2]);
    float c0 = cosf(t[0]), c1 = cosf(t[1]), c2 = cosf(t[2]);
    R[0] = c1 * c2; R[1] = s0 * s1 * c2 - s2 * c0; R[2] = s1 * c0 * c2 + s0 * s2;
    R[3] = s2 * c1; R[4] = s0 * s1 * s2 + c0 * c2; R[5] = s1 * s2 * c0 - s0 * c2;
    R[6] = -s1;     R[7] = s0 * c1;                R[8] = c0 * c1;
}

__device__ inline void splat1(float x, float y, float zz, const float R[9],
                              unsigned* lcnt) {
    float cx = R[0] * x + R[1] * y + R[2] * zz;
    float cy = R[3] * x + R[4] * y + R[5] * zz;
    float cz = R[6] * x + R[7] * y + R[8] * zz;
    float z  = cz + 2.5f;
    float u  = 120.0f * cx / z + 36.0f;
    float v  = 120.0f * cy / z + 36.0f;
    int x4 = (int)rintf(u);   // round-half-even, matches jnp.round
    int y4 = (int)rintf(v);
    if (x4 >= 0 && x4 <= 64 && y4 >= 0 && y4 <= 64)
        atomicAdd(&lcnt[x4 * CNT_W + y4], 1u);
}

// ---------------- histogram: per-(image,split) partial counts ----------------
// grid: NIMG*NSPLIT = 256 blocks, 512 threads
__global__ __launch_bounds__(512) void hist_kernel(const float* __restrict__ pc1,
                                                   const float* __restrict__ pc2,
                                                   const float* __restrict__ rot,
                                                   unsigned* __restrict__ pcnts,
                                                   float* __restrict__ out) {
    __shared__ unsigned lcnt[CNT_SZ];
    int bid   = blockIdx.x;
    int split = bid & (NSPLIT - 1);
    int imgi  = bid >> 2;               // r*32 + c*16 + b
    int b = imgi & 15;
    int c = (imgi >> 4) & 1;
    int r = imgi >> 5;
    int tid = threadIdx.x;

    if (bid == 0 && tid == 0) out[0] = 0.0f;   // stream-ordered before convbce

    for (int i = tid; i < CNT_SZ; i += 512) lcnt[i] = 0u;

    float R[9];
    eul2rot(rot + 3 * r, R);
    const float* pc = (c ? pc2 : pc1) + (size_t)b * NPTS * 3;
    const float4* pc4 = (const float4*)pc;
    __syncthreads();

    // each group g covers points 4g..4g+3 (48 contiguous bytes = 3 float4)
    int gend = (split + 1) * GPS;
    for (int g = split * GPS + tid; g < gend; g += 512) {
        float4 a = pc4[3 * g + 0];
        float4 bq = pc4[3 * g + 1];
        float4 cq = pc4[3 * g + 2];
        splat1(a.x, a.y, a.z, R, lcnt);
        splat1(a.w, bq.x, bq.y, R, lcnt);
        splat1(bq.z, bq.w, cq.x, R, lcnt);
        splat1(cq.y, cq.z, cq.w, R, lcnt);
    }
    __syncthreads();

    unsigned* g = pcnts + (size_t)bid * CNT_SZ;
    for (int i = tid; i < CNT_SZ; i += 512) g[i] = lcnt[i];
}

// ---------------- fused conv(5x5) + per-image max + BCE ----------------
// grid: 32 blocks (one per (r,b) pair), 1024 threads
__global__ __launch_bounds__(1024) void convbce_kernel(const unsigned* __restrict__ pcnts,
                                                       float* __restrict__ out) {
    __shared__ float lcA[CNT_SZ];
    __shared__ float lcB[CNT_SZ];
    __shared__ float redA[16], redB[16], redS[16];
    int bid = blockIdx.x;        // r*16 + b
    int b = bid & 15, r = bid >> 4;
    int i1 = r * 32 + b;          // pc1 image
    int i2 = r * 32 + 16 + b;     // pc2 image
    int tid = threadIdx.x;

    const unsigned* pa = pcnts + (size_t)i1 * NSPLIT * CNT_SZ;
    const unsigned* pb = pcnts + (size_t)i2 * NSPLIT * CNT_SZ;
    for (int i = tid; i < CNT_SZ; i += 1024) {
        lcA[i] = (float)(pa[i] + pa[i + CNT_SZ] + pa[i + 2 * CNT_SZ] + pa[i + 3 * CNT_SZ]);
        lcB[i] = (float)(pb[i] + pb[i + CNT_SZ] + pb[i + 2 * CNT_SZ] + pb[i + 3 * CNT_SZ]);
    }

    // GK[i][j] = exp(-sqrt((i-5)^2+(j-5)^2)/0.4), i,j in 0..4
    float GK[25];
#pragma unroll
    for (int i = 0; i < 5; i++)
#pragma unroll
        for (int j = 0; j < 5; j++) {
            float d = sqrtf((float)((i - 5) * (i - 5) + (j - 5) * (j - 5)));
            GK[i * 5 + j] = expf(-d / 0.4f);
        }
    __syncthreads();

    // conv: 4 outputs per image per thread, held in registers
    float cA[4], cB[4];
    float mA = 0.0f, mB = 0.0f;
#pragma unroll
    for (int k = 0; k < 4; k++) {
        int o = tid + k * 1024;
        int px = o >> 6, py = o & 63;
        float sA = 0.0f, sB = 0.0f;
#pragma unroll
        for (int i = 0; i < 5; i++) {
            int x = px + 2 + i;
            if (x > 64) continue;
            const float* rowA = &lcA[x * CNT_W];
            const float* rowB = &lcB[x * CNT_W];
#pragma unroll
            for (int j = 0; j < 5; j++) {
                int y = py + 2 + j;
                if (y > 64) continue;
                float w = GK[i * 5 + j];
                sA += w * rowA[y];
                sB += w * rowB[y];
            }
        }
        cA[k] = sA; cB[k] = sB;
        mA = fmaxf(mA, sA); mB = fmaxf(mB, sB);
    }

    // block max reduce (16 waves)
#pragma unroll
    for (int off = 32; off > 0; off >>= 1) {
        mA = fmaxf(mA, __shfl_down(mA, off));
        mB = fmaxf(mB, __shfl_down(mB, off));
    }
    int wave = tid >> 6;
    if ((tid & 63) == 0) { redA[wave] = mA; redB[wave] = mB; }
    __syncthreads();
    float maxA = redA[0], maxB = redB[0];
#pragma unroll
    for (int w = 1; w < 16; w++) {
        maxA = fmaxf(maxA, redA[w]);
        maxB = fmaxf(maxB, redB[w]);
    }

    float invA = 1.0f / maxA, invB = 1.0f / maxB;
    float s = 0.0f;
#pragma unroll
    for (int k = 0; k < 4; k++) {
        float e1 = cA[k] * invA;
        float e2 = cB[k] * invB;
        float lp = fmaxf(logf(e1), -100.0f);
        float lq = fmaxf(logf(1.0f - e1), -100.0f);
        s += e2 * lp + (1.0f - e2) * lq;
    }
#pragma unroll
    for (int off = 32; off > 0; off >>= 1) s += __shfl_down(s, off);
    if ((tid & 63) == 0) redS[wave] = s;
    __syncthreads();
    if (tid == 0) {
        float tot = 0.0f;
#pragma unroll
        for (int w = 0; w < 16; w++) tot += redS[w];
        atomicAdd(out, -tot);
    }
}

extern "C" void kernel_launch(void* const* d_in, const int* in_sizes, int n_in,
                              void* d_out, int out_size, void* d_ws, size_t ws_size,
                              hipStream_t stream) {
    const float* pc1 = (const float*)d_in[0];
    const float* pc2 = (const float*)d_in[1];
    const float* rot = (const float*)d_in[2];
    float* out = (float*)d_out;

    unsigned* pcnts = (unsigned*)d_ws;   // NIMG*NSPLIT * 4225 u32 = 4.3 MB

    hist_kernel<<<NIMG * NSPLIT, 512, 0, stream>>>(pc1, pc2, rot, pcnts, out);
    convbce_kernel<<<32, 1024, 0, stream>>>(pcnts, out);
}